// Round 9
// baseline (1378.461 us; speedup 1.0000x reference)
//
#include <hip/hip_runtime.h>
#include <hip/hip_bf16.h>
#include <math.h>

// Problem constants
#define S_LEN 2048
#define DIM   2048
#define H_N   16
#define NOPE  128
#define ROPE  64
#define VD    128
#define LORA  512
#define D_QK  576
#define SCALE_F 0.07216878364870323f   // 192^-0.5
#define EPS_F 1e-6f
#define KVF 640                        // padded kv row (f32 elems)
#define KVS 1280                       // padded kv row (shorts)

typedef short short8 __attribute__((ext_vector_type(8)));
typedef short short4v __attribute__((ext_vector_type(4)));
typedef float floatx4 __attribute__((ext_vector_type(4)));

static __device__ inline unsigned short f2bf_bits(float f) {
  union { __hip_bfloat16 h; unsigned short u; } cv;
  cv.h = __float2bfloat16(f);
  return cv.u;
}

// global_load_lds: LDS destination must be WAVE-UNIFORM; lane's 16B lands at
// base + lane*16 automatically.
static __device__ inline void gload_lds16(const short* gptr, short* lds_base_uniform) {
  __builtin_amdgcn_global_load_lds(
      (const __attribute__((address_space(1))) void*)gptr,
      (__attribute__((address_space(3))) void*)lds_base_uniform, 16, 0, 0);
}

// ---------------------------------------------------------------------------
// elementwise f32 -> bf16 cast, 8 elts/thread
// ---------------------------------------------------------------------------
__global__ __launch_bounds__(256) void cast_f32_bf16(
    const float* __restrict__ src, short* __restrict__ dst, int n8) {
  int i = blockIdx.x * 256 + threadIdx.x;
  if (i < n8) {
    float4 a = ((const float4*)src)[2 * i];
    float4 b = ((const float4*)src)[2 * i + 1];
    uint4 o;
    o.x = (unsigned)f2bf_bits(a.x) | ((unsigned)f2bf_bits(a.y) << 16);
    o.y = (unsigned)f2bf_bits(a.z) | ((unsigned)f2bf_bits(a.w) << 16);
    o.z = (unsigned)f2bf_bits(b.x) | ((unsigned)f2bf_bits(b.y) << 16);
    o.w = (unsigned)f2bf_bits(b.z) | ((unsigned)f2bf_bits(b.w) << 16);
    ((uint4*)dst)[i] = o;
  }
}

// zero n8 uint4-chunks (8 shorts each)
__global__ __launch_bounds__(256) void zero_short8(short* __restrict__ dst, int n8) {
  int i = blockIdx.x * 256 + threadIdx.x;
  if (i < n8) ((uint4*)dst)[i] = (uint4){0u, 0u, 0u, 0u};
}

// ---------------------------------------------------------------------------
// wukT[h][c][d] = wkv_b[h*256 + d][c]  (f32 in, bf16 out), c<512, d<128
// ---------------------------------------------------------------------------
__global__ __launch_bounds__(256) void transpose_wuk(
    const float* __restrict__ wkvb, short* __restrict__ wukT) {
  __shared__ float tile[32][33];
  const int h = blockIdx.z, c0 = blockIdx.y * 32, d0 = blockIdx.x * 32;
  const int t = threadIdx.x;
  const int r = t >> 3, c4 = (t & 7) * 4;
  float4 v = *(const float4*)(wkvb + ((long)h * 256 + d0 + r) * 512 + c0 + c4);
  tile[r][c4 + 0] = v.x; tile[r][c4 + 1] = v.y;
  tile[r][c4 + 2] = v.z; tile[r][c4 + 3] = v.w;
  __syncthreads();
  uint2 o;
  o.x = (unsigned)f2bf_bits(tile[c4 + 0][r]) | ((unsigned)f2bf_bits(tile[c4 + 1][r]) << 16);
  o.y = (unsigned)f2bf_bits(tile[c4 + 2][r]) | ((unsigned)f2bf_bits(tile[c4 + 3][r]) << 16);
  *(uint2*)(wukT + ((long)h * 512 + c0 + r) * 128 + d0 + c4) = o;
}

// ---------------------------------------------------------------------------
// bf16 MFMA NT GEMM: C[m,n] = sum_k A[m,k]*B[n,k], f32 out. (unchanged, r6)
// ---------------------------------------------------------------------------
__global__ __launch_bounds__(256) void gemm_bf16_nt(
    const short* __restrict__ A, const short* __restrict__ B, float* __restrict__ C,
    int K, int lda, int ldb, int ldc, long aB, long bB, long cB) {
  A += (long)blockIdx.z * aB;
  B += (long)blockIdx.z * bB;
  C += (long)blockIdx.z * cB;
  const int m0 = blockIdx.y * 128, n0 = blockIdx.x * 128;
  __shared__ short As[128 * 32];
  __shared__ short Bs[128 * 32];
  const int tid = threadIdx.x, w = tid >> 6, lane = tid & 63;
  const int ln = lane & 15, g = lane >> 4;
  const int mw = (w & 1) * 64, nw = (w >> 1) * 64;
  floatx4 acc[4][4];
#pragma unroll
  for (int i = 0; i < 4; ++i)
#pragma unroll
    for (int j = 0; j < 4; ++j) acc[i][j] = (floatx4){0.f, 0.f, 0.f, 0.f};

  for (int k0 = 0; k0 < K; k0 += 32) {
    __syncthreads();
#pragma unroll
    for (int i = 0; i < 2; ++i) {
      const int bc = (i * 4 + w) * 64;          // wave-uniform base chunk
      const int c = bc + lane;
      const int row = c >> 2, quar = c & 3;
      gload_lds16(A + (long)(m0 + row) * lda + k0 + quar * 8, As + bc * 8);
      gload_lds16(B + (long)(n0 + row) * ldb + k0 + quar * 8, Bs + bc * 8);
    }
    __syncthreads();
    short8 af[4], bf_[4];
#pragma unroll
    for (int mi = 0; mi < 4; ++mi)
      af[mi] = *(const short8*)(As + (mw + mi * 16 + ln) * 32 + g * 8);
#pragma unroll
    for (int ni = 0; ni < 4; ++ni)
      bf_[ni] = *(const short8*)(Bs + (nw + ni * 16 + ln) * 32 + g * 8);
#pragma unroll
    for (int mi = 0; mi < 4; ++mi)
#pragma unroll
      for (int ni = 0; ni < 4; ++ni)
        acc[mi][ni] = __builtin_amdgcn_mfma_f32_16x16x32_bf16(af[mi], bf_[ni], acc[mi][ni], 0, 0, 0);
  }
#pragma unroll
  for (int mi = 0; mi < 4; ++mi)
#pragma unroll
    for (int ni = 0; ni < 4; ++ni)
#pragma unroll
      for (int r = 0; r < 4; ++r)
        C[(long)(m0 + mw + mi * 16 + g * 4 + r) * ldc + n0 + nw + ni * 16 + ln] = acc[mi][ni][r];
}

// ---------------------------------------------------------------------------
// prep: RMSNorm + RoPE on kv rows (f32 stride KVF) -> bf16 in place (short
// stride KVS, first 576 valid); q_pe RoPE -> qhat tail f32  (unchanged)
// ---------------------------------------------------------------------------
__global__ __launch_bounds__(64) void prep_kernel(
    float* kv, const float* __restrict__ qbuf, float* __restrict__ qhat,
    const float* __restrict__ cosp, const float* __restrict__ sinp,
    const float* __restrict__ normw) {
  const int s = blockIdx.x;
  const int l = threadIdx.x;
  float* row = kv + (long)s * KVF;
  short* krow = (short*)kv + (long)s * KVS;

  float4 v0 = *(const float4*)(row + l * 8);
  float4 v1 = *(const float4*)(row + l * 8 + 4);
  float rx0 = 0.f, rx1 = 0.f, rc = 0.f, rs = 0.f;
  if (l < 32) {
    rc = cosp[s * 32 + l];
    rs = sinp[s * 32 + l];
    rx0 = row[512 + 2 * l];
    rx1 = row[512 + 2 * l + 1];
  }
  float4 w0 = *(const float4*)(normw + l * 8);
  float4 w1 = *(const float4*)(normw + l * 8 + 4);

  float ss = v0.x * v0.x + v0.y * v0.y + v0.z * v0.z + v0.w * v0.w +
             v1.x * v1.x + v1.y * v1.y + v1.z * v1.z + v1.w * v1.w;
#pragma unroll
  for (int off = 32; off; off >>= 1) ss += __shfl_xor(ss, off, 64);
  const float scale = rsqrtf(ss * (1.0f / (float)LORA) + EPS_F);
  v0.x *= scale * w0.x; v0.y *= scale * w0.y; v0.z *= scale * w0.z; v0.w *= scale * w0.w;
  v1.x *= scale * w1.x; v1.y *= scale * w1.y; v1.z *= scale * w1.z; v1.w *= scale * w1.w;

  uint4 pk;
  pk.x = (unsigned)f2bf_bits(v0.x) | ((unsigned)f2bf_bits(v0.y) << 16);
  pk.y = (unsigned)f2bf_bits(v0.z) | ((unsigned)f2bf_bits(v0.w) << 16);
  pk.z = (unsigned)f2bf_bits(v1.x) | ((unsigned)f2bf_bits(v1.y) << 16);
  pk.w = (unsigned)f2bf_bits(v1.z) | ((unsigned)f2bf_bits(v1.w) << 16);
  *(uint4*)(krow + l * 8) = pk;

  if (l < 32) {
    const float y0 = rx0 * rc - rx1 * rs;
    const float y1 = rx0 * rs + rx1 * rc;
    unsigned pr = (unsigned)f2bf_bits(y0) | ((unsigned)f2bf_bits(y1) << 16);
    *(unsigned*)(krow + 512 + 2 * l) = pr;
  }

#pragma unroll
  for (int it = 0; it < 8; ++it) {
    const int p = it * 64 + l;
    const int h = p >> 5;
    const int i = p & 31;
    const float c = cosp[s * 32 + i];
    const float sn = sinp[s * 32 + i];
    const float* qp = qbuf + (long)s * (H_N * 192) + h * 192 + NOPE;
    const float x0 = qp[2 * i];
    const float x1 = qp[2 * i + 1];
    float* dst = qhat + ((long)h * S_LEN + s) * D_QK + 512;
    dst[2 * i]     = x0 * c - x1 * sn;
    dst[2 * i + 1] = x0 * sn + x1 * c;
  }
}

// ---------------------------------------------------------------------------
// Transpose V: kvt[d][s] = kbf[s][d], d<512. kbf rows stride KVS shorts.
// ---------------------------------------------------------------------------
__global__ __launch_bounds__(256) void transpose_v(
    const short* __restrict__ kbf, short* __restrict__ kvt) {
  __shared__ short tile[32][36];
  const int d0 = blockIdx.x * 32;
  const int s0 = blockIdx.y * 32;
  const int t = threadIdx.x;
  const int r = t >> 3;
  const int c4 = (t & 7) * 4;
  uint2 v = *(const uint2*)(kbf + (long)(s0 + r) * KVS + d0 + c4);
  *(uint2*)(&tile[r][c4]) = v;
  __syncthreads();
  uint2 o;
  o.x = (unsigned)(unsigned short)tile[c4 + 0][r] | ((unsigned)(unsigned short)tile[c4 + 1][r] << 16);
  o.y = (unsigned)(unsigned short)tile[c4 + 2][r] | ((unsigned)(unsigned short)tile[c4 + 3][r] << 16);
  *(uint2*)(kvt + (long)(d0 + r) * S_LEN + s0 + c4) = o;
}

// ---------------------------------------------------------------------------
// Fragment-major K: ktt[kt][c][lane][8]  (unchanged, r7)
// ---------------------------------------------------------------------------
__global__ __launch_bounds__(256) void build_ktt(
    const short* __restrict__ kbf, short* __restrict__ ktt) {
  const int kt = blockIdx.x;                     // 0..127
  for (int idx = threadIdx.x; idx < 18 * 64; idx += 256) {
    const int c = idx >> 6, l = idx & 63;
    const int ln = l & 15, g = l >> 4;
    uint4 v = *(const uint4*)(kbf + (long)(kt * 16 + ln) * KVS + c * 32 + g * 8);
    *(uint4*)(ktt + ((long)(kt * 18 + c) * 64 + l) * 8) = v;
  }
}

// ---------------------------------------------------------------------------
// Fragment-major V^T: vtt[kt][nt][lane][8]  (unchanged, r7)
// ---------------------------------------------------------------------------
__global__ __launch_bounds__(256) void build_vtt(
    const short* __restrict__ kvt, short* __restrict__ vtt) {
  const int kt = blockIdx.x;                     // 0..63
  for (int idx = threadIdx.x; idx < 32 * 64; idx += 256) {
    const int nt = idx >> 6, l = idx & 63;
    const int ln = l & 15, g = l >> 4;
    uint4 v = *(const uint4*)(kvt + (long)(nt * 16 + ln) * S_LEN + kt * 32 + g * 8);
    *(uint4*)(vtt + ((long)(kt * 32 + nt) * 64 + l) * 8) = v;
  }
}

// ---------------------------------------------------------------------------
// Register flash v4: Q moved to LDS (frag-major, 18KB), freeing 72 VGPRs/wave
// so K/V loads can stay in flight. Block = 128 thr = 2 waves (dh=0/1 of one
// (16q, head)); one barrier after Q staging, then barrier-free (LDS read-only).
// Inner math identical to round 8 (passed). 8 blocks/CU by LDS -> 16 waves/CU.
// ---------------------------------------------------------------------------
__global__ __launch_bounds__(128, 4) void flash_reg(
    const float* __restrict__ qhat,   // [H][S][576] f32
    const short* __restrict__ ktt,    // [128][18][64][8] bf16 frag-major K
    const short* __restrict__ vtt,    // [64][32][64][8] bf16 frag-major V^T
    float* __restrict__ obuf) {       // [H][S][512] f32
  const int bid = blockIdx.x;         // 0..2047
  const int h = bid & 15;
  const int u = bid >> 4;             // 0..127
  const int a = u >> 4, b = u & 15;
  const int base = ((a >> 1) << 4) + b;
  const int qw = (a & 1) ? (127 - base) : base;
  const int q0 = qw * 16;
  const int tid = threadIdx.x;
  const int dh = tid >> 6;
  const int lane = tid & 63;
  const int ln = lane & 15, g = lane >> 4;
  const int vbase = dh * 256;
  const int qlim = q0 + ln;

  __shared__ short Qs[18 * 64 * 8];   // frag-major Q, 18 KB

  // ---- cooperative Q stage: chunk idx = c*64+l, 16B each ----
  for (int idx = tid; idx < 18 * 64; idx += 128) {
    const int c = idx >> 6, l = idx & 63;
    const int lln = l & 15, lg = l >> 4;
    const float* src = qhat + ((long)h * S_LEN + q0 + lln) * D_QK + c * 32 + lg * 8;
    floatx4 x = __builtin_nontemporal_load((const floatx4*)src);
    floatx4 y = __builtin_nontemporal_load((const floatx4*)(src + 4));
    short8 f;
    f[0] = (short)f2bf_bits(x[0]); f[1] = (short)f2bf_bits(x[1]);
    f[2] = (short)f2bf_bits(x[2]); f[3] = (short)f2bf_bits(x[3]);
    f[4] = (short)f2bf_bits(y[0]); f[5] = (short)f2bf_bits(y[1]);
    f[6] = (short)f2bf_bits(y[2]); f[7] = (short)f2bf_bits(y[3]);
    *(short8*)(Qs + idx * 8) = f;
  }
  __syncthreads();

  floatx4 oacc[16];
#pragma unroll
  for (int nt = 0; nt < 16; ++nt) oacc[nt] = (floatx4){0.f, 0.f, 0.f, 0.f};
  float lsum = 0.f;

  const int nsteps = (qw + 2) >> 1;   // 32-key steps

  for (int s = 0; s < nsteps; ++s) {
    const int t0 = s * 32;
    // ---- QK^T: two 16-key tiles; Q frags from LDS, K frags streaming ----
    const short* kA = ktt + (long)(2 * s) * 18 * 512 + lane * 8;
    const short* kB = kA + 18 * 512;
    floatx4 sA0 = {0.f,0.f,0.f,0.f}, sA1 = {0.f,0.f,0.f,0.f};
    floatx4 sB0 = {0.f,0.f,0.f,0.f}, sB1 = {0.f,0.f,0.f,0.f};
#pragma unroll
    for (int c = 0; c < 18; c += 2) {
      short8 q0v = *(const short8*)(Qs + (c * 64 + lane) * 8);
      short8 q1v = *(const short8*)(Qs + ((c + 1) * 64 + lane) * 8);
      short8 ka0 = *(const short8*)(kA + c * 512);
      short8 ka1 = *(const short8*)(kA + (c + 1) * 512);
      short8 kb0 = *(const short8*)(kB + c * 512);
      short8 kb1 = *(const short8*)(kB + (c + 1) * 512);
      sA0 = __builtin_amdgcn_mfma_f32_16x16x32_bf16(ka0, q0v, sA0, 0, 0, 0);
      sB0 = __builtin_amdgcn_mfma_f32_16x16x32_bf16(kb0, q0v, sB0, 0, 0, 0);
      sA1 = __builtin_amdgcn_mfma_f32_16x16x32_bf16(ka1, q1v, sA1, 0, 0, 0);
      sB1 = __builtin_amdgcn_mfma_f32_16x16x32_bf16(kb1, q1v, sB1, 0, 0, 0);
    }
    // ---- exp + causal mask; tile A keys t0+4g+r, tile B keys t0+16+4g+r ----
    short4v pA4, pB4;
    float psum = 0.f;
#pragma unroll
    for (int r = 0; r < 4; ++r) {
      const int kAi = t0 + g * 4 + r;
      const int kBi = kAi + 16;
      float scA = fminf(fmaxf((sA0[r] + sA1[r]) * SCALE_F, -30.f), 30.f);
      float scB = fminf(fmaxf((sB0[r] + sB1[r]) * SCALE_F, -30.f), 30.f);
      float pA = (kAi <= qlim) ? __expf(scA) : 0.f;
      float pB = (kBi <= qlim) ? __expf(scB) : 0.f;
      psum += pA + pB;
      pA4[r] = (short)f2bf_bits(pA);
      pB4[r] = (short)f2bf_bits(pB);
    }
    lsum += psum;
    // ---- build P^T B-frag for K=32 (same shuffle net as round 7/8) ----
    union { short4v s; int i[2]; } ua, ub;
    ua.s = pA4; ub.s = pB4;
    const int lolane = ln + ((g & 1) << 5);
    const int hilane = lolane + 16;
    int alo0 = __shfl(ua.i[0], lolane, 64), alo1 = __shfl(ua.i[1], lolane, 64);
    int ahi0 = __shfl(ua.i[0], hilane, 64), ahi1 = __shfl(ua.i[1], hilane, 64);
    int blo0 = __shfl(ub.i[0], lolane, 64), blo1 = __shfl(ub.i[1], lolane, 64);
    int bhi0 = __shfl(ub.i[0], hilane, 64), bhi1 = __shfl(ub.i[1], hilane, 64);
    union { short8 s; int i[4]; } up;
    const bool useA = (g < 2);
    up.i[0] = useA ? alo0 : blo0;
    up.i[1] = useA ? alo1 : blo1;
    up.i[2] = useA ? ahi0 : bhi0;
    up.i[3] = useA ? ahi1 : bhi1;
    const short8 pb8 = up.s;
    // ---- PV: frag-major streaming V loads, K=32 ----
    const short* vp = vtt + (((long)s * 32 + dh * 16) * 64 + lane) * 8;
#pragma unroll
    for (int half = 0; half < 2; ++half) {
      short8 va[8];
#pragma unroll
      for (int j = 0; j < 8; ++j)
        va[j] = *(const short8*)(vp + (half * 8 + j) * 512);
#pragma unroll
      for (int j = 0; j < 8; ++j)
        oacc[half * 8 + j] = __builtin_amdgcn_mfma_f32_16x16x32_bf16(va[j], pb8, oacc[half * 8 + j], 0, 0, 0);
    }
  }

  // denominator for query q0+ln: sum over g-groups (within this wave)
  lsum += __shfl_xor(lsum, 16, 64);
  lsum += __shfl_xor(lsum, 32, 64);
  const float inv = 1.0f / fmaxf(lsum, 1e-30f);

  // O^T tile: row=g*4+r -> d = vbase+nt*16+g*4+r, col=ln -> query q0+ln
  float* orow = obuf + ((long)h * S_LEN + q0 + ln) * 512 + vbase + g * 4;
#pragma unroll
  for (int nt = 0; nt < 16; ++nt) {
    floatx4 st = {oacc[nt][0] * inv, oacc[nt][1] * inv, oacc[nt][2] * inv, oacc[nt][3] * inv};
    __builtin_nontemporal_store(st, (floatx4*)(orow + nt * 16));
  }
}

// ---------------------------------------------------------------------------
// Host launch
// ---------------------------------------------------------------------------
extern "C" void kernel_launch(void* const* d_in, const int* in_sizes, int n_in,
                              void* d_out, int out_size, void* d_ws, size_t ws_size,
                              hipStream_t stream) {
  (void)in_sizes; (void)n_in; (void)out_size; (void)ws_size;
  const float* x      = (const float*)d_in[0];
  const float* cosp   = (const float*)d_in[1];
  const float* sinp   = (const float*)d_in[2];
  const float* wq     = (const float*)d_in[3];
  const float* wkv_a  = (const float*)d_in[4];
  const float* normw  = (const float*)d_in[5];
  const float* wkv_b  = (const float*)d_in[6];
  const float* wo     = (const float*)d_in[7];
  float* out = (float*)d_out;

  float* ws = (float*)d_ws;
  float* qbuf  = ws;                                   // [S,3072] f32 (25.2 MB)
  float* kvold = qbuf  + (long)S_LEN * 3072;           // wkv_a-pad bf16 region
  float* qhat  = kvold + (long)S_LEN * D_QK;           // [H,S,576] f32
  float* obuf  = qhat  + (long)H_N * S_LEN * D_QK;     // [H,S,512] f32
  float* oproj = obuf  + (long)H_N * S_LEN * LORA;     // [S,2048] f32

  // padded kv: [S, KVF] f32 in the oproj region (dead until step 10)
  float* kvpad = oproj;                                // 5.24 MB <= 16.8 MB
  short* kbf = (short*)kvpad;                          // bf16 rows stride KVS
  short* wkvap = (short*)kvold;                        // padded wkv_a bf16 [KVF,2048]

  // K/V transform buffers in the qbuf region (qbuf f32 dead after step 5):
  short* kvt = (short*)qbuf;                           // [512][S] bf16, 2 MB
  short* ktt = kvt + (long)512 * S_LEN;                // 2.36 MB frag-major K
  short* vtt = ktt + (long)128 * 18 * 64 * 8;          // 2 MB frag-major V^T

  // bf16 scratch aliased into obuf region (dead until flash):
  short* xb    = (short*)obuf;                         // 2048x2048
  short* wqb   = xb  + (long)2048 * 2048;              // 3072x2048
  short* qbufb = wqb + (long)3072 * 2048;              // 2048x3072
  short* wukT  = qbufb + (long)2048 * 3072;            // 16x512x128
  // bf16 scratch aliased into qhat region (dead after flash):
  short* obufb  = (short*)qhat;                        // 16x2048x512
  short* wkvbb  = obufb + (long)H_N * S_LEN * 512;     // 4096x512
  short* oprojb = wkvbb + (long)4096 * 512;            // 2048x2048
  short* wob    = oprojb + (long)2048 * 2048;          // 2048x2048

  // 1) casts for projections
  cast_f32_bf16<<<dim3(2048), 256, 0, stream>>>(x, xb, 2048 * 2048 / 8);
  cast_f32_bf16<<<dim3(3072), 256, 0, stream>>>(wq, wqb, 3072 * 2048 / 8);
  cast_f32_bf16<<<dim3(576), 256, 0, stream>>>(wkv_a, wkvap, 576 * 2048 / 8);
  zero_short8<<<dim3(64), 256, 0, stream>>>(wkvap + 576L * 2048, 64 * 2048 / 8);

  // 2) qbuf = x @ wq^T  (bf16 MFMA)
  gemm_bf16_nt<<<dim3(3072 / 128, 2048 / 128, 1), 256, 0, stream>>>(
      xb, wqb, qbuf, 2048, 2048, 2048, 3072, 0, 0, 0);

  // 3) kvpad = x @ wkv_a_pad^T  (bf16 MFMA, N=640 incl. 64 zero rows)
  gemm_bf16_nt<<<dim3(KVF / 128, 2048 / 128, 1), 256, 0, stream>>>(
      xb, wkvap, kvpad, 2048, 2048, 2048, KVF, 0, 0, 0);

  // 4) RMSNorm + RoPE (kvpad -> kbf bf16 in place; q_pe -> qhat tail f32)
  prep_kernel<<<dim3(S_LEN), 64, 0, stream>>>(kvpad, qbuf, qhat, cosp, sinp, normw);

  // 5) cast qbuf -> qbufb ; build wukT
  cast_f32_bf16<<<dim3(3072), 256, 0, stream>>>(qbuf, qbufb, 2048 * 3072 / 8);
  transpose_wuk<<<dim3(4, 16, 16), 256, 0, stream>>>(wkv_b, wukT);

  // 6) qhat[:, :512] = q_nope @ w_uk  (batched bf16 MFMA NT vs wukT)
  gemm_bf16_nt<<<dim3(512 / 128, 2048 / 128, 16), 256, 0, stream>>>(
      qbufb, wukT, qhat, 128, 3072, 128, 576,
      192L, 512L * 128, (long)S_LEN * D_QK);

  // 7) K/V layout transforms (qbuf region free after step 5)
  transpose_v<<<dim3(16, 64), 256, 0, stream>>>(kbf, kvt);
  build_ktt<<<dim3(128), 256, 0, stream>>>(kbf, ktt);
  build_vtt<<<dim3(64), 256, 0, stream>>>(kvt, vtt);

  // 8) flash attention -> obuf  (block = 2 waves: dh 0/1 of one (q,h))
  flash_reg<<<dim3(2048), 128, 0, stream>>>(qhat, ktt, vtt, obuf);

  // 9) casts for output projections
  cast_f32_bf16<<<dim3(8192), 256, 0, stream>>>(obuf, obufb, H_N * S_LEN * 512 / 8);
  cast_f32_bf16<<<dim3(1024), 256, 0, stream>>>(wkv_b, wkvbb, 4096 * 512 / 8);

  // 10) oproj[s, h*128+d] = sum_c obuf[h,s,c] * w_uv[h,d,c]  (kvpad dead now)
  gemm_bf16_nt<<<dim3(1, 2048 / 128, 16), 256, 0, stream>>>(
      obufb, wkvbb + 128L * 512, oproj, 512, 512, 512, 2048,
      (long)S_LEN * 512, 256L * 512, 128L);

  // 11) out = oproj @ wo^T
  cast_f32_bf16<<<dim3(2048), 256, 0, stream>>>(oproj, oprojb, 2048 * 2048 / 8);
  cast_f32_bf16<<<dim3(2048), 256, 0, stream>>>(wo, wob, 2048 * 2048 / 8);
  gemm_bf16_nt<<<dim3(2048 / 128, 2048 / 128, 1), 256, 0, stream>>>(
      oprojb, wob, out, 2048, 2048, 2048, 2048, 0, 0, 0);
}

// Round 10
// 604.329 us; speedup vs baseline: 2.2810x; 2.2810x over previous
//
#include <hip/hip_runtime.h>
#include <hip/hip_bf16.h>
#include <math.h>

// Problem constants
#define S_LEN 2048
#define DIM   2048
#define H_N   16
#define NOPE  128
#define ROPE  64
#define VD    128
#define LORA  512
#define D_QK  576
#define SCALE_F 0.07216878364870323f   // 192^-0.5
#define EPS_F 1e-6f
#define KVF 640                        // padded kv row (f32 elems)
#define KVS 1280                       // padded kv row (shorts)

typedef short short8 __attribute__((ext_vector_type(8)));
typedef short short4v __attribute__((ext_vector_type(4)));
typedef float floatx4 __attribute__((ext_vector_type(4)));

static __device__ inline unsigned short f2bf_bits(float f) {
  union { __hip_bfloat16 h; unsigned short u; } cv;
  cv.h = __float2bfloat16(f);
  return cv.u;
}

// global_load_lds: LDS destination must be WAVE-UNIFORM; lane's 16B lands at
// base + lane*16 automatically.
static __device__ inline void gload_lds16(const short* gptr, short* lds_base_uniform) {
  __builtin_amdgcn_global_load_lds(
      (const __attribute__((address_space(1))) void*)gptr,
      (__attribute__((address_space(3))) void*)lds_base_uniform, 16, 0, 0);
}

// ---------------------------------------------------------------------------
// elementwise f32 -> bf16 cast, 8 elts/thread
// ---------------------------------------------------------------------------
__global__ __launch_bounds__(256) void cast_f32_bf16(
    const float* __restrict__ src, short* __restrict__ dst, int n8) {
  int i = blockIdx.x * 256 + threadIdx.x;
  if (i < n8) {
    float4 a = ((const float4*)src)[2 * i];
    float4 b = ((const float4*)src)[2 * i + 1];
    uint4 o;
    o.x = (unsigned)f2bf_bits(a.x) | ((unsigned)f2bf_bits(a.y) << 16);
    o.y = (unsigned)f2bf_bits(a.z) | ((unsigned)f2bf_bits(a.w) << 16);
    o.z = (unsigned)f2bf_bits(b.x) | ((unsigned)f2bf_bits(b.y) << 16);
    o.w = (unsigned)f2bf_bits(b.z) | ((unsigned)f2bf_bits(b.w) << 16);
    ((uint4*)dst)[i] = o;
  }
}

// zero n8 uint4-chunks (8 shorts each)
__global__ __launch_bounds__(256) void zero_short8(short* __restrict__ dst, int n8) {
  int i = blockIdx.x * 256 + threadIdx.x;
  if (i < n8) ((uint4*)dst)[i] = (uint4){0u, 0u, 0u, 0u};
}

// ---------------------------------------------------------------------------
// wukT[h][c][d] = wkv_b[h*256 + d][c]  (f32 in, bf16 out), c<512, d<128
// ---------------------------------------------------------------------------
__global__ __launch_bounds__(256) void transpose_wuk(
    const float* __restrict__ wkvb, short* __restrict__ wukT) {
  __shared__ float tile[32][33];
  const int h = blockIdx.z, c0 = blockIdx.y * 32, d0 = blockIdx.x * 32;
  const int t = threadIdx.x;
  const int r = t >> 3, c4 = (t & 7) * 4;
  float4 v = *(const float4*)(wkvb + ((long)h * 256 + d0 + r) * 512 + c0 + c4);
  tile[r][c4 + 0] = v.x; tile[r][c4 + 1] = v.y;
  tile[r][c4 + 2] = v.z; tile[r][c4 + 3] = v.w;
  __syncthreads();
  uint2 o;
  o.x = (unsigned)f2bf_bits(tile[c4 + 0][r]) | ((unsigned)f2bf_bits(tile[c4 + 1][r]) << 16);
  o.y = (unsigned)f2bf_bits(tile[c4 + 2][r]) | ((unsigned)f2bf_bits(tile[c4 + 3][r]) << 16);
  *(uint2*)(wukT + ((long)h * 512 + c0 + r) * 128 + d0 + c4) = o;
}

// ---------------------------------------------------------------------------
// bf16 MFMA NT GEMM: C[m,n] = sum_k A[m,k]*B[n,k], f32 out. (unchanged, r6)
// ---------------------------------------------------------------------------
__global__ __launch_bounds__(256) void gemm_bf16_nt(
    const short* __restrict__ A, const short* __restrict__ B, float* __restrict__ C,
    int K, int lda, int ldb, int ldc, long aB, long bB, long cB) {
  A += (long)blockIdx.z * aB;
  B += (long)blockIdx.z * bB;
  C += (long)blockIdx.z * cB;
  const int m0 = blockIdx.y * 128, n0 = blockIdx.x * 128;
  __shared__ short As[128 * 32];
  __shared__ short Bs[128 * 32];
  const int tid = threadIdx.x, w = tid >> 6, lane = tid & 63;
  const int ln = lane & 15, g = lane >> 4;
  const int mw = (w & 1) * 64, nw = (w >> 1) * 64;
  floatx4 acc[4][4];
#pragma unroll
  for (int i = 0; i < 4; ++i)
#pragma unroll
    for (int j = 0; j < 4; ++j) acc[i][j] = (floatx4){0.f, 0.f, 0.f, 0.f};

  for (int k0 = 0; k0 < K; k0 += 32) {
    __syncthreads();
#pragma unroll
    for (int i = 0; i < 2; ++i) {
      const int bc = (i * 4 + w) * 64;          // wave-uniform base chunk
      const int c = bc + lane;
      const int row = c >> 2, quar = c & 3;
      gload_lds16(A + (long)(m0 + row) * lda + k0 + quar * 8, As + bc * 8);
      gload_lds16(B + (long)(n0 + row) * ldb + k0 + quar * 8, Bs + bc * 8);
    }
    __syncthreads();
    short8 af[4], bf_[4];
#pragma unroll
    for (int mi = 0; mi < 4; ++mi)
      af[mi] = *(const short8*)(As + (mw + mi * 16 + ln) * 32 + g * 8);
#pragma unroll
    for (int ni = 0; ni < 4; ++ni)
      bf_[ni] = *(const short8*)(Bs + (nw + ni * 16 + ln) * 32 + g * 8);
#pragma unroll
    for (int mi = 0; mi < 4; ++mi)
#pragma unroll
      for (int ni = 0; ni < 4; ++ni)
        acc[mi][ni] = __builtin_amdgcn_mfma_f32_16x16x32_bf16(af[mi], bf_[ni], acc[mi][ni], 0, 0, 0);
  }
#pragma unroll
  for (int mi = 0; mi < 4; ++mi)
#pragma unroll
    for (int ni = 0; ni < 4; ++ni)
#pragma unroll
      for (int r = 0; r < 4; ++r)
        C[(long)(m0 + mw + mi * 16 + g * 4 + r) * ldc + n0 + nw + ni * 16 + ln] = acc[mi][ni][r];
}

// ---------------------------------------------------------------------------
// prep: RMSNorm + RoPE on kv rows (f32 stride KVF) -> bf16 in place (short
// stride KVS, first 576 valid); q_pe RoPE -> qhat tail f32  (unchanged)
// ---------------------------------------------------------------------------
__global__ __launch_bounds__(64) void prep_kernel(
    float* kv, const float* __restrict__ qbuf, float* __restrict__ qhat,
    const float* __restrict__ cosp, const float* __restrict__ sinp,
    const float* __restrict__ normw) {
  const int s = blockIdx.x;
  const int l = threadIdx.x;
  float* row = kv + (long)s * KVF;
  short* krow = (short*)kv + (long)s * KVS;

  float4 v0 = *(const float4*)(row + l * 8);
  float4 v1 = *(const float4*)(row + l * 8 + 4);
  float rx0 = 0.f, rx1 = 0.f, rc = 0.f, rs = 0.f;
  if (l < 32) {
    rc = cosp[s * 32 + l];
    rs = sinp[s * 32 + l];
    rx0 = row[512 + 2 * l];
    rx1 = row[512 + 2 * l + 1];
  }
  float4 w0 = *(const float4*)(normw + l * 8);
  float4 w1 = *(const float4*)(normw + l * 8 + 4);

  float ss = v0.x * v0.x + v0.y * v0.y + v0.z * v0.z + v0.w * v0.w +
             v1.x * v1.x + v1.y * v1.y + v1.z * v1.z + v1.w * v1.w;
#pragma unroll
  for (int off = 32; off; off >>= 1) ss += __shfl_xor(ss, off, 64);
  const float scale = rsqrtf(ss * (1.0f / (float)LORA) + EPS_F);
  v0.x *= scale * w0.x; v0.y *= scale * w0.y; v0.z *= scale * w0.z; v0.w *= scale * w0.w;
  v1.x *= scale * w1.x; v1.y *= scale * w1.y; v1.z *= scale * w1.z; v1.w *= scale * w1.w;

  uint4 pk;
  pk.x = (unsigned)f2bf_bits(v0.x) | ((unsigned)f2bf_bits(v0.y) << 16);
  pk.y = (unsigned)f2bf_bits(v0.z) | ((unsigned)f2bf_bits(v0.w) << 16);
  pk.z = (unsigned)f2bf_bits(v1.x) | ((unsigned)f2bf_bits(v1.y) << 16);
  pk.w = (unsigned)f2bf_bits(v1.z) | ((unsigned)f2bf_bits(v1.w) << 16);
  *(uint4*)(krow + l * 8) = pk;

  if (l < 32) {
    const float y0 = rx0 * rc - rx1 * rs;
    const float y1 = rx0 * rs + rx1 * rc;
    unsigned pr = (unsigned)f2bf_bits(y0) | ((unsigned)f2bf_bits(y1) << 16);
    *(unsigned*)(krow + 512 + 2 * l) = pr;
  }

#pragma unroll
  for (int it = 0; it < 8; ++it) {
    const int p = it * 64 + l;
    const int h = p >> 5;
    const int i = p & 31;
    const float c = cosp[s * 32 + i];
    const float sn = sinp[s * 32 + i];
    const float* qp = qbuf + (long)s * (H_N * 192) + h * 192 + NOPE;
    const float x0 = qp[2 * i];
    const float x1 = qp[2 * i + 1];
    float* dst = qhat + ((long)h * S_LEN + s) * D_QK + 512;
    dst[2 * i]     = x0 * c - x1 * sn;
    dst[2 * i + 1] = x0 * sn + x1 * c;
  }
}

// ---------------------------------------------------------------------------
// Transpose V: kvt[d][s] = kbf[s][d], d<512. kbf rows stride KVS shorts.
// ---------------------------------------------------------------------------
__global__ __launch_bounds__(256) void transpose_v(
    const short* __restrict__ kbf, short* __restrict__ kvt) {
  __shared__ short tile[32][36];
  const int d0 = blockIdx.x * 32;
  const int s0 = blockIdx.y * 32;
  const int t = threadIdx.x;
  const int r = t >> 3;
  const int c4 = (t & 7) * 4;
  uint2 v = *(const uint2*)(kbf + (long)(s0 + r) * KVS + d0 + c4);
  *(uint2*)(&tile[r][c4]) = v;
  __syncthreads();
  uint2 o;
  o.x = (unsigned)(unsigned short)tile[c4 + 0][r] | ((unsigned)(unsigned short)tile[c4 + 1][r] << 16);
  o.y = (unsigned)(unsigned short)tile[c4 + 2][r] | ((unsigned)(unsigned short)tile[c4 + 3][r] << 16);
  *(uint2*)(kvt + (long)(d0 + r) * S_LEN + s0 + c4) = o;
}

// ---------------------------------------------------------------------------
// Fragment-major K: ktt[kt][c][lane][8]  (unchanged, r7)
// ---------------------------------------------------------------------------
__global__ __launch_bounds__(256) void build_ktt(
    const short* __restrict__ kbf, short* __restrict__ ktt) {
  const int kt = blockIdx.x;                     // 0..127
  for (int idx = threadIdx.x; idx < 18 * 64; idx += 256) {
    const int c = idx >> 6, l = idx & 63;
    const int ln = l & 15, g = l >> 4;
    uint4 v = *(const uint4*)(kbf + (long)(kt * 16 + ln) * KVS + c * 32 + g * 8);
    *(uint4*)(ktt + ((long)(kt * 18 + c) * 64 + l) * 8) = v;
  }
}

// ---------------------------------------------------------------------------
// Fragment-major V^T: vtt[kt][nt][lane][8]  (unchanged, r7)
// ---------------------------------------------------------------------------
__global__ __launch_bounds__(256) void build_vtt(
    const short* __restrict__ kvt, short* __restrict__ vtt) {
  const int kt = blockIdx.x;                     // 0..63
  for (int idx = threadIdx.x; idx < 32 * 64; idx += 256) {
    const int nt = idx >> 6, l = idx & 63;
    const int ln = l & 15, g = l >> 4;
    uint4 v = *(const uint4*)(kvt + (long)(nt * 16 + ln) * S_LEN + kt * 32 + g * 8);
    *(uint4*)(vtt + ((long)(kt * 32 + nt) * 64 + l) * 8) = v;
  }
}

// ---------------------------------------------------------------------------
// Flash v6: block = 256 thr = 4 waves = (2 heads x 2 dh) of one q-tile.
// Per 32-key step the block DMA-stages the K tile (36 KB, contiguous in
// frag-major ktt) into LDS via global_load_lds (deep-queue MLP, m97 pattern),
// then each wave reads its QK A-frags with ds_read_b128. V frags stream
// direct from L2 (16 independent loads/wave). K bytes shared by 4 waves.
// Inner math identical to round 8 (passed). launch_bounds(256,2): generous
// VGPR budget -- round 9's spill disaster came from over-constraining.
// ---------------------------------------------------------------------------
__global__ __launch_bounds__(256, 2) void flash_reg(
    const float* __restrict__ qhat,   // [H][S][576] f32
    const short* __restrict__ ktt,    // [128][18][64][8] bf16 frag-major K
    const short* __restrict__ vtt,    // [64][32][64][8] bf16 frag-major V^T
    float* __restrict__ obuf) {       // [H][S][512] f32
  const int bid = blockIdx.x;         // 0..1023
  const int hp = bid & 7;             // head pair
  const int u = bid >> 3;             // 0..127
  const int a = u >> 4, b = u & 15;
  const int base = ((a >> 1) << 4) + b;
  const int qw = (a & 1) ? (127 - base) : base;
  const int q0 = qw * 16;
  const int tid = threadIdx.x;
  const int w = tid >> 6;             // wave 0..3
  const int lane = tid & 63;
  const int ln = lane & 15, g = lane >> 4;
  const int h = hp * 2 + (w & 1);
  const int dh = w >> 1;
  const int vbase = dh * 256;
  const int qlim = q0 + ln;

  __shared__ short Kt[36 * 64 * 8];   // 36 KB: key-tiles 2s (chunks 0-17), 2s+1 (18-35)

  // Q B-frags for this wave's head: n = ln (query), k = g*8+j
  short8 qfr[18];
  {
    const float* qrow = qhat + ((long)h * S_LEN + q0 + ln) * D_QK;
#pragma unroll
    for (int c = 0; c < 18; ++c) {
      floatx4 x = __builtin_nontemporal_load((const floatx4*)(qrow + c * 32 + g * 8));
      floatx4 y = __builtin_nontemporal_load((const floatx4*)(qrow + c * 32 + g * 8 + 4));
      short8 f;
      f[0] = (short)f2bf_bits(x[0]); f[1] = (short)f2bf_bits(x[1]);
      f[2] = (short)f2bf_bits(x[2]); f[3] = (short)f2bf_bits(x[3]);
      f[4] = (short)f2bf_bits(y[0]); f[5] = (short)f2bf_bits(y[1]);
      f[6] = (short)f2bf_bits(y[2]); f[7] = (short)f2bf_bits(y[3]);
      qfr[c] = f;
    }
  }

  floatx4 oacc[16];
#pragma unroll
  for (int nt = 0; nt < 16; ++nt) oacc[nt] = (floatx4){0.f, 0.f, 0.f, 0.f};
  float lsum = 0.f;

  const int nsteps = (qw + 2) >> 1;   // 32-key steps

  for (int s = 0; s < nsteps; ++s) {
    const int t0 = s * 32;
    // ---- DMA-stage K tile pair (36 KB linear copy from ktt) ----
    const short* ksrc = ktt + (long)(2 * s) * 18 * 512;   // 2304 16B-chunks
    __syncthreads();
#pragma unroll
    for (int i = 0; i < 9; ++i) {
      const int bc = (i * 4 + w) * 64;          // wave-uniform base chunk
      gload_lds16(ksrc + (long)(bc + lane) * 8, Kt + bc * 8);
    }
    __syncthreads();
    // ---- QK^T: two 16-key tiles; K frags from LDS ----
    floatx4 sA0 = {0.f,0.f,0.f,0.f}, sA1 = {0.f,0.f,0.f,0.f};
    floatx4 sB0 = {0.f,0.f,0.f,0.f}, sB1 = {0.f,0.f,0.f,0.f};
#pragma unroll
    for (int c = 0; c < 18; c += 2) {
      short8 ka0 = *(const short8*)(Kt + (c * 64 + lane) * 8);
      short8 ka1 = *(const short8*)(Kt + ((c + 1) * 64 + lane) * 8);
      short8 kb0 = *(const short8*)(Kt + ((18 + c) * 64 + lane) * 8);
      short8 kb1 = *(const short8*)(Kt + ((19 + c) * 64 + lane) * 8);
      sA0 = __builtin_amdgcn_mfma_f32_16x16x32_bf16(ka0, qfr[c], sA0, 0, 0, 0);
      sB0 = __builtin_amdgcn_mfma_f32_16x16x32_bf16(kb0, qfr[c], sB0, 0, 0, 0);
      sA1 = __builtin_amdgcn_mfma_f32_16x16x32_bf16(ka1, qfr[c + 1], sA1, 0, 0, 0);
      sB1 = __builtin_amdgcn_mfma_f32_16x16x32_bf16(kb1, qfr[c + 1], sB1, 0, 0, 0);
    }
    // ---- exp + causal mask; tile A keys t0+4g+r, tile B keys t0+16+4g+r ----
    short4v pA4, pB4;
    float psum = 0.f;
#pragma unroll
    for (int r = 0; r < 4; ++r) {
      const int kAi = t0 + g * 4 + r;
      const int kBi = kAi + 16;
      float scA = fminf(fmaxf((sA0[r] + sA1[r]) * SCALE_F, -30.f), 30.f);
      float scB = fminf(fmaxf((sB0[r] + sB1[r]) * SCALE_F, -30.f), 30.f);
      float pA = (kAi <= qlim) ? __expf(scA) : 0.f;
      float pB = (kBi <= qlim) ? __expf(scB) : 0.f;
      psum += pA + pB;
      pA4[r] = (short)f2bf_bits(pA);
      pB4[r] = (short)f2bf_bits(pB);
    }
    lsum += psum;
    // ---- build P^T B-frag for K=32 (same shuffle net as rounds 7/8) ----
    union { short4v s; int i[2]; } ua, ub;
    ua.s = pA4; ub.s = pB4;
    const int lolane = ln + ((g & 1) << 5);
    const int hilane = lolane + 16;
    int alo0 = __shfl(ua.i[0], lolane, 64), alo1 = __shfl(ua.i[1], lolane, 64);
    int ahi0 = __shfl(ua.i[0], hilane, 64), ahi1 = __shfl(ua.i[1], hilane, 64);
    int blo0 = __shfl(ub.i[0], lolane, 64), blo1 = __shfl(ub.i[1], lolane, 64);
    int bhi0 = __shfl(ub.i[0], hilane, 64), bhi1 = __shfl(ub.i[1], hilane, 64);
    union { short8 s; int i[4]; } up;
    const bool useA = (g < 2);
    up.i[0] = useA ? alo0 : blo0;
    up.i[1] = useA ? alo1 : blo1;
    up.i[2] = useA ? ahi0 : bhi0;
    up.i[3] = useA ? ahi1 : bhi1;
    const short8 pb8 = up.s;
    // ---- PV: frag-major streaming V loads from L2, K=32 ----
    const short* vp = vtt + (((long)s * 32 + dh * 16) * 64 + lane) * 8;
#pragma unroll
    for (int half = 0; half < 2; ++half) {
      short8 va[8];
#pragma unroll
      for (int j = 0; j < 8; ++j)
        va[j] = *(const short8*)(vp + (half * 8 + j) * 512);
#pragma unroll
      for (int j = 0; j < 8; ++j)
        oacc[half * 8 + j] = __builtin_amdgcn_mfma_f32_16x16x32_bf16(va[j], pb8, oacc[half * 8 + j], 0, 0, 0);
    }
  }

  // denominator for query q0+ln: sum over g-groups (within this wave)
  lsum += __shfl_xor(lsum, 16, 64);
  lsum += __shfl_xor(lsum, 32, 64);
  const float inv = 1.0f / fmaxf(lsum, 1e-30f);

  // O^T tile: row=g*4+r -> d = vbase+nt*16+g*4+r, col=ln -> query q0+ln
  float* orow = obuf + ((long)h * S_LEN + q0 + ln) * 512 + vbase + g * 4;
#pragma unroll
  for (int nt = 0; nt < 16; ++nt) {
    floatx4 st = {oacc[nt][0] * inv, oacc[nt][1] * inv, oacc[nt][2] * inv, oacc[nt][3] * inv};
    __builtin_nontemporal_store(st, (floatx4*)(orow + nt * 16));
  }
}

// ---------------------------------------------------------------------------
// Host launch
// ---------------------------------------------------------------------------
extern "C" void kernel_launch(void* const* d_in, const int* in_sizes, int n_in,
                              void* d_out, int out_size, void* d_ws, size_t ws_size,
                              hipStream_t stream) {
  (void)in_sizes; (void)n_in; (void)out_size; (void)ws_size;
  const float* x      = (const float*)d_in[0];
  const float* cosp   = (const float*)d_in[1];
  const float* sinp   = (const float*)d_in[2];
  const float* wq     = (const float*)d_in[3];
  const float* wkv_a  = (const float*)d_in[4];
  const float* normw  = (const float*)d_in[5];
  const float* wkv_b  = (const float*)d_in[6];
  const float* wo     = (const float*)d_in[7];
  float* out = (float*)d_out;

  float* ws = (float*)d_ws;
  float* qbuf  = ws;                                   // [S,3072] f32 (25.2 MB)
  float* kvold = qbuf  + (long)S_LEN * 3072;           // wkv_a-pad bf16 region
  float* qhat  = kvold + (long)S_LEN * D_QK;           // [H,S,576] f32
  float* obuf  = qhat  + (long)H_N * S_LEN * D_QK;     // [H,S,512] f32
  float* oproj = obuf  + (long)H_N * S_LEN * LORA;     // [S,2048] f32

  // padded kv: [S, KVF] f32 in the oproj region (dead until step 10)
  float* kvpad = oproj;                                // 5.24 MB <= 16.8 MB
  short* kbf = (short*)kvpad;                          // bf16 rows stride KVS
  short* wkvap = (short*)kvold;                        // padded wkv_a bf16 [KVF,2048]

  // K/V transform buffers in the qbuf region (qbuf f32 dead after step 5):
  short* kvt = (short*)qbuf;                           // [512][S] bf16, 2 MB
  short* ktt = kvt + (long)512 * S_LEN;                // 2.36 MB frag-major K
  short* vtt = ktt + (long)128 * 18 * 64 * 8;          // 2 MB frag-major V^T

  // bf16 scratch aliased into obuf region (dead until flash):
  short* xb    = (short*)obuf;                         // 2048x2048
  short* wqb   = xb  + (long)2048 * 2048;              // 3072x2048
  short* qbufb = wqb + (long)3072 * 2048;              // 2048x3072
  short* wukT  = qbufb + (long)2048 * 3072;            // 16x512x128
  // bf16 scratch aliased into qhat region (dead after flash):
  short* obufb  = (short*)qhat;                        // 16x2048x512
  short* wkvbb  = obufb + (long)H_N * S_LEN * 512;     // 4096x512
  short* oprojb = wkvbb + (long)4096 * 512;            // 2048x2048
  short* wob    = oprojb + (long)2048 * 2048;          // 2048x2048

  // 1) casts for projections
  cast_f32_bf16<<<dim3(2048), 256, 0, stream>>>(x, xb, 2048 * 2048 / 8);
  cast_f32_bf16<<<dim3(3072), 256, 0, stream>>>(wq, wqb, 3072 * 2048 / 8);
  cast_f32_bf16<<<dim3(576), 256, 0, stream>>>(wkv_a, wkvap, 576 * 2048 / 8);
  zero_short8<<<dim3(64), 256, 0, stream>>>(wkvap + 576L * 2048, 64 * 2048 / 8);

  // 2) qbuf = x @ wq^T  (bf16 MFMA)
  gemm_bf16_nt<<<dim3(3072 / 128, 2048 / 128, 1), 256, 0, stream>>>(
      xb, wqb, qbuf, 2048, 2048, 2048, 3072, 0, 0, 0);

  // 3) kvpad = x @ wkv_a_pad^T  (bf16 MFMA, N=640 incl. 64 zero rows)
  gemm_bf16_nt<<<dim3(KVF / 128, 2048 / 128, 1), 256, 0, stream>>>(
      xb, wkvap, kvpad, 2048, 2048, 2048, KVF, 0, 0, 0);

  // 4) RMSNorm + RoPE (kvpad -> kbf bf16 in place; q_pe -> qhat tail f32)
  prep_kernel<<<dim3(S_LEN), 64, 0, stream>>>(kvpad, qbuf, qhat, cosp, sinp, normw);

  // 5) cast qbuf -> qbufb ; build wukT
  cast_f32_bf16<<<dim3(3072), 256, 0, stream>>>(qbuf, qbufb, 2048 * 3072 / 8);
  transpose_wuk<<<dim3(4, 16, 16), 256, 0, stream>>>(wkv_b, wukT);

  // 6) qhat[:, :512] = q_nope @ w_uk  (batched bf16 MFMA NT vs wukT)
  gemm_bf16_nt<<<dim3(512 / 128, 2048 / 128, 16), 256, 0, stream>>>(
      qbufb, wukT, qhat, 128, 3072, 128, 576,
      192L, 512L * 128, (long)S_LEN * D_QK);

  // 7) K/V layout transforms (qbuf region free after step 5)
  transpose_v<<<dim3(16, 64), 256, 0, stream>>>(kbf, kvt);
  build_ktt<<<dim3(128), 256, 0, stream>>>(kbf, ktt);
  build_vtt<<<dim3(64), 256, 0, stream>>>(kvt, vtt);

  // 8) flash attention -> obuf  (block = 4 waves: 2 heads x 2 dh, shared K)
  flash_reg<<<dim3(1024), 256, 0, stream>>>(qhat, ktt, vtt, obuf);

  // 9) casts for output projections
  cast_f32_bf16<<<dim3(8192), 256, 0, stream>>>(obuf, obufb, H_N * S_LEN * 512 / 8);
  cast_f32_bf16<<<dim3(1024), 256, 0, stream>>>(wkv_b, wkvbb, 4096 * 512 / 8);

  // 10) oproj[s, h*128+d] = sum_c obuf[h,s,c] * w_uv[h,d,c]  (kvpad dead now)
  gemm_bf16_nt<<<dim3(1, 2048 / 128, 16), 256, 0, stream>>>(
      obufb, wkvbb + 128L * 512, oproj, 512, 512, 512, 2048,
      (long)S_LEN * 512, 256L * 512, 128L);

  // 11) out = oproj @ wo^T
  cast_f32_bf16<<<dim3(2048), 256, 0, stream>>>(oproj, oprojb, 2048 * 2048 / 8);
  cast_f32_bf16<<<dim3(2048), 256, 0, stream>>>(wo, wob, 2048 * 2048 / 8);
  gemm_bf16_nt<<<dim3(2048 / 128, 2048 / 128, 1), 256, 0, stream>>>(
      oprojb, wob, out, 2048, 2048, 2048, 2048, 0, 0, 0);
}